// Round 5
// baseline (1700.649 us; speedup 1.0000x reference)
//
#include <hip/hip_runtime.h>
#include <math.h>

#define NPTS 2048
#define BATCH 4
#define RTOT 8192   // BATCH*NPTS
#define KNN16 16

typedef unsigned long long u64;
typedef unsigned int u32;
typedef unsigned short ush;

using short8  = __attribute__((ext_vector_type(8))) short;
using float4v = __attribute__((ext_vector_type(4))) float;

// counter slots
#define CTR_G1 0
#define CTR_G2 1
#define CTR_G3 2
#define CTR_G4 3
#define CTR_M21 4
#define CTR_M31 5
#define CTR_M5 6
#define CTR_RED 7

static __device__ __forceinline__ float lrelu_f(float v) {
  return v >= 0.f ? v : 0.2f * v;
}

// round-to-nearest-even fp32 -> bf16, also return remainder
static __device__ __forceinline__ ush bf16_rne(float f, float* rem) {
  u32 u = __float_as_uint(f);
  u32 r = u + 0x7FFFu + ((u >> 16) & 1u);
  ush h = (ush)(r >> 16);
  *rem = f - __uint_as_float((u32)h << 16);
  return h;
}

static __device__ __forceinline__ void w_split(float v, ush* hi, ush* lo, size_t i) {
  float rem, rem2;
  hi[i] = bf16_rne(v, &rem);
  lo[i] = bf16_rne(rem, &rem2);
}

static __device__ __forceinline__ float edge_w_val(const float* __restrict__ W, int O, int C, int i) {
  int o = i / C, c = i % C;
  return (o < O) ? W[(size_t)o * 2 * C + c]
                 : (W[(size_t)(o - O) * 2 * C + C + c] - W[(size_t)(o - O) * 2 * C + c]);
}

// ============ prep_all: all weight preps + counter zeroing (1 dispatch) =====
__global__ __launch_bounds__(256) void prep_all(
    const float* __restrict__ conv1_w, const float* __restrict__ conv2_w,
    const float* __restrict__ conv2_1_w, const float* __restrict__ conv3_w,
    const float* __restrict__ conv3_1_w, const float* __restrict__ conv4_w,
    const float* __restrict__ conv5_w,
    float* __restrict__ ws1, ush* __restrict__ ws2hi, ush* __restrict__ ws2lo,
    ush* __restrict__ ws3hi, ush* __restrict__ ws3lo,
    ush* __restrict__ ws4hi, ush* __restrict__ ws4lo,
    ush* __restrict__ c21hi, ush* __restrict__ c21lo,
    ush* __restrict__ c31hi, ush* __restrict__ c31lo,
    ush* __restrict__ c5hi, ush* __restrict__ c5lo,
    u32* __restrict__ counters) {
  if (blockIdx.x == 0 && threadIdx.x < 16) counters[threadIdx.x] = 0;
  int gi = blockIdx.x * 256 + threadIdx.x;
  if (gi < 384) {  // conv1 stacked fp32 (O=64, C=3)
    ws1[gi] = edge_w_val(conv1_w, 64, 3, gi);
    return;
  }
  gi -= 384;
  if (gi < 8192) { w_split(edge_w_val(conv2_w, 64, 64, gi), ws2hi, ws2lo, gi); return; }
  gi -= 8192;
  if (gi < 32768) { w_split(edge_w_val(conv3_w, 128, 128, gi), ws3hi, ws3lo, gi); return; }
  gi -= 32768;
  if (gi < 262144) { w_split(edge_w_val(conv4_w, 512, 256, gi), ws4hi, ws4lo, gi); return; }
  gi -= 262144;
  if (gi < 16384) { w_split(conv2_1_w[gi], c21hi, c21lo, gi); return; }
  gi -= 16384;
  if (gi < 65536) { w_split(conv3_1_w[gi], c31hi, c31lo, gi); return; }
  gi -= 65536;
  if (gi < 786432) { w_split(conv5_w[gi], c5hi, c5lo, gi); return; }
}

// ====================== KNN top-16, two-pass, register CE chain =============
#define REP16(X) X(0) X(1) X(2) X(3) X(4) X(5) X(6) X(7) X(8) X(9) X(10) X(11) X(12) X(13) X(14) X(15)

__global__ __launch_bounds__(256) void knn16_part(const float* __restrict__ x,
                                                  u64* __restrict__ pkeys) {
  __shared__ float4 cand[256];
  const int tid = threadIdx.x;
  const int qchunk = blockIdx.x, slice = blockIdx.y, b = blockIdx.z;
  const float* xb = x + (size_t)b * NPTS * 3;
  {
    const int c = slice * 256 + tid;
    float a0 = xb[c * 3 + 0], a1 = xb[c * 3 + 1], a2 = xb[c * 3 + 2];
    cand[tid] = make_float4(a0, a1, a2, a0 * a0 + a1 * a1 + a2 * a2);
  }
  const int n = qchunk * 256 + tid;
  const float p0 = xb[n * 3 + 0], p1 = xb[n * 3 + 1], p2 = xb[n * 3 + 2];
  const float pw = p0 * p0 + p1 * p1 + p2 * p2;
  __syncthreads();
#define DECLK(k) u64 key##k = 0ull;
  REP16(DECLK)
#undef DECLK
  const int mbase = slice * 256;
  for (int m2 = 0; m2 < 256; m2++) {
    const float4 qd = cand[m2];
    const float dot = p0 * qd.x + p1 * qd.y + p2 * qd.z;
    const float inner = -2.0f * dot;
    const float pd = -pw - inner - qd.w;
    u32 s = __float_as_uint(pd);
    s = (s & 0x80000000u) ? ~s : (s | 0x80000000u);
    u64 ck = ((u64)s << 32) | (u32)(2047 - (mbase + m2));
#define CE(k) { const bool sw = ck > key##k; const u64 mx = sw ? ck : key##k; \
                const u64 mn = sw ? key##k : ck; key##k = mx; ck = mn; }
    REP16(CE)
#undef CE
  }
  const size_t q = (size_t)b * NPTS + n;
#define STOREK(k) pkeys[(size_t)(slice * 16 + k) * RTOT + q] = key##k;
  REP16(STOREK)
#undef STOREK
}

__global__ __launch_bounds__(256) void knn16_merge(const u64* __restrict__ pkeys,
                                                   int* __restrict__ idxout) {
  const int q = blockIdx.x * 256 + threadIdx.x;
#define DECLK(k) u64 key##k = 0ull;
  REP16(DECLK)
#undef DECLK
  for (int j = 0; j < 128; j++) {
    u64 ck = pkeys[(size_t)j * RTOT + q];
#define CE(k) { const bool sw = ck > key##k; const u64 mx = sw ? ck : key##k; \
                const u64 mn = sw ? key##k : ck; key##k = mx; ck = mn; }
    REP16(CE)
#undef CE
  }
  int* op = idxout + (size_t)q * KNN16;
#define STOREI(k) op[k] = 2047 - (int)(key##k & 0xFFFFFFFFu);
  REP16(STOREI)
#undef STOREI
}

// ============ conv1 fully fused: gemm(K=3) + gather + stats =================
__global__ __launch_bounds__(256) void edge_conv1(
    const float* __restrict__ x, const int* __restrict__ idx,
    const float* __restrict__ ws1, float* __restrict__ xcat,
    double* __restrict__ parts, u32* __restrict__ counter,
    float* __restrict__ smean, float* __restrict__ sinv) {
  __shared__ float xs0[NPTS], xs1[NPTS], xs2[NPTS];  // 24KB
  __shared__ int sidx[128 * KNN16];                  // 8KB
  __shared__ double sred[256 * 5];                   // 10KB
  const int tid = threadIdx.x;
  const int row0 = blockIdx.x * 128;
  const int b = row0 >> 11;
  const float* xb = x + (size_t)b * NPTS * 3;
  for (int t = tid; t < NPTS * 3; t += 256) {
    int p = t / 3, c = t - p * 3;
    float v = xb[t];
    if (c == 0) xs0[p] = v; else if (c == 1) xs1[p] = v; else xs2[p] = v;
  }
  for (int t = tid; t < 128 * KNN16; t += 256) sidx[t] = idx[(size_t)row0 * KNN16 + t];
  __syncthreads();
  const int o = tid & 63, sub = tid >> 6;
  const float wd0 = ws1[o * 3 + 0], wd1 = ws1[o * 3 + 1], wd2 = ws1[o * 3 + 2];
  const float wc0 = ws1[(64 + o) * 3 + 0], wc1 = ws1[(64 + o) * 3 + 1], wc2 = ws1[(64 + o) * 3 + 2];
  double s1 = 0, s2 = 0, scr = 0, sc = 0, sc2 = 0;
  for (int nl = sub; nl < 128; nl += 4) {
    const int r = row0 + nl;
    const int lp = (r & 2047);
    const float yc = wc0 * xs0[lp] + wc1 * xs1[lp] + wc2 * xs2[lp];
    const int* ip = &sidx[nl * KNN16];
    float m = -INFINITY, a1 = 0.f, a2 = 0.f;
#pragma unroll
    for (int k = 0; k < KNN16; k++) {
      const int nb = ip[k];
      const float yd = wd0 * xs0[nb] + wd1 * xs1[nb] + wd2 * xs2[nb];
      m = fmaxf(m, yd);
      a1 += yd;
      a2 = fmaf(yd, yd, a2);
    }
    xcat[(size_t)r * 768 + o] = yc + m;
    s1 += a1; s2 += a2; scr += (double)yc * (double)a1;
    sc += yc; sc2 += (double)yc * (double)yc;
  }
  sred[tid * 5 + 0] = s1; sred[tid * 5 + 1] = s2; sred[tid * 5 + 2] = scr;
  sred[tid * 5 + 3] = sc; sred[tid * 5 + 4] = sc2;
  __syncthreads();
  if (sub == 0) {
    for (int j = 1; j < 4; j++) {
      const int t2 = tid + j * 64;
      s1 += sred[t2 * 5 + 0]; s2 += sred[t2 * 5 + 1]; scr += sred[t2 * 5 + 2];
      sc += sred[t2 * 5 + 3]; sc2 += sred[t2 * 5 + 4];
    }
    double* pp = &parts[((size_t)blockIdx.x * 64 + o) * 5];
    pp[0] = s1; pp[1] = s2; pp[2] = scr; pp[3] = sc; pp[4] = sc2;
  }
  __threadfence();
  __syncthreads();
  __shared__ u32 isLast;
  if (tid == 0) isLast = (atomicAdd(counter, 1u) == 63u);
  __syncthreads();
  if (isLast) {
    __threadfence();
    const volatile double* vp = (const volatile double*)parts;
    if (tid < 64) {
      double t1 = 0, t2 = 0, tcr = 0, tc = 0, tc2 = 0;
      for (int k = 0; k < 64; k++) {
        const size_t p = ((size_t)k * 64 + tid) * 5;
        t1 += vp[p]; t2 += vp[p + 1]; tcr += vp[p + 2]; tc += vp[p + 3]; tc2 += vp[p + 4];
      }
      const double cnt = (double)RTOT * KNN16;
      double mv = (t1 + (double)KNN16 * tc) / cnt;
      double ev2 = (t2 + 2.0 * tcr + (double)KNN16 * tc2) / cnt;
      smean[tid] = (float)mv;
      sinv[tid] = (float)(1.0 / sqrt(ev2 - mv * mv + 1e-5));
    }
  }
}

// ============ bf16x3 MFMA GEMM with lazy-BN F staging + optional out stats ==
#define LDSP 40

__global__ __launch_bounds__(256, 2) void gemm_bn(
    const float* __restrict__ F, int ldF,
    const float* __restrict__ fmean, const float* __restrict__ finv,
    const ush* __restrict__ Whi, const ush* __restrict__ Wlo,
    float* __restrict__ Out, int ldOut, int outOff, int K,
    double* __restrict__ oparts, u32* __restrict__ counter,
    float* __restrict__ omean, float* __restrict__ oinv) {
  __shared__ __align__(16) ush sFhi[128 * LDSP], sFlo[128 * LDSP];
  __shared__ __align__(16) ush sWhi[128 * LDSP], sWlo[128 * LDSP];
  __shared__ float sM[768], sI[768];
  const int tid = threadIdx.x;
  const int obase = blockIdx.x * 128, rbase = blockIdx.y * 128;
  const int wave = tid >> 6, lane = tid & 63;
  const int wrow = (wave >> 1) * 64, wcol = (wave & 1) * 64;
  const int l15 = lane & 15, quad = lane >> 4;
  for (int i = tid; i < K; i += 256) { sM[i] = fmean[i]; sI[i] = finv[i]; }
  float4v acc[4][4];
#pragma unroll
  for (int i = 0; i < 4; i++)
#pragma unroll
    for (int j = 0; j < 4; j++) acc[i][j] = (float4v){0.f, 0.f, 0.f, 0.f};
  const int srow = tid >> 1, skk = (tid & 1) * 16;
  const int sdst = srow * LDSP + skk;
  __syncthreads();
  for (int k0 = 0; k0 < K; k0 += 32) {
    const size_t wb = (size_t)(obase + srow) * K + k0 + skk;
    uint4 wh0 = *(const uint4*)&Whi[wb];
    uint4 wh1 = *(const uint4*)&Whi[wb + 8];
    uint4 wl0 = *(const uint4*)&Wlo[wb];
    uint4 wl1 = *(const uint4*)&Wlo[wb + 8];
    float fv[16];
    {
      const float* fp = &F[(size_t)(rbase + srow) * ldF + k0 + skk];
      *(float4*)&fv[0] = *(const float4*)&fp[0];
      *(float4*)&fv[4] = *(const float4*)&fp[4];
      *(float4*)&fv[8] = *(const float4*)&fp[8];
      *(float4*)&fv[12] = *(const float4*)&fp[12];
    }
    u32 hp[8], lp[8];
#pragma unroll
    for (int e = 0; e < 8; e++) {
      const int kk = k0 + skk + e * 2;
      float v0 = lrelu_f((fv[e * 2] - sM[kk]) * sI[kk]);
      float v1 = lrelu_f((fv[e * 2 + 1] - sM[kk + 1]) * sI[kk + 1]);
      float r0, r1, d0, d1;
      ush h0 = bf16_rne(v0, &r0);
      ush h1 = bf16_rne(v1, &r1);
      ush l0 = bf16_rne(r0, &d0);
      ush l1 = bf16_rne(r1, &d1);
      hp[e] = (u32)h0 | ((u32)h1 << 16);
      lp[e] = (u32)l0 | ((u32)l1 << 16);
    }
    *(uint4*)&sFhi[sdst] = make_uint4(hp[0], hp[1], hp[2], hp[3]);
    *(uint4*)&sFhi[sdst + 8] = make_uint4(hp[4], hp[5], hp[6], hp[7]);
    *(uint4*)&sFlo[sdst] = make_uint4(lp[0], lp[1], lp[2], lp[3]);
    *(uint4*)&sFlo[sdst + 8] = make_uint4(lp[4], lp[5], lp[6], lp[7]);
    *(uint4*)&sWhi[sdst] = wh0;
    *(uint4*)&sWhi[sdst + 8] = wh1;
    *(uint4*)&sWlo[sdst] = wl0;
    *(uint4*)&sWlo[sdst + 8] = wl1;
    __syncthreads();
    short8 afh[4], afl[4], bfh[4], bfl[4];
#pragma unroll
    for (int i = 0; i < 4; i++) {
      const int ar = (wrow + i * 16 + l15) * LDSP + quad * 8;
      const int br = (wcol + i * 16 + l15) * LDSP + quad * 8;
      afh[i] = *(const short8*)&sFhi[ar];
      afl[i] = *(const short8*)&sFlo[ar];
      bfh[i] = *(const short8*)&sWhi[br];
      bfl[i] = *(const short8*)&sWlo[br];
    }
#pragma unroll
    for (int i = 0; i < 4; i++)
#pragma unroll
      for (int j = 0; j < 4; j++) {
        acc[i][j] = __builtin_amdgcn_mfma_f32_16x16x32_bf16(afh[i], bfh[j], acc[i][j], 0, 0, 0);
        acc[i][j] = __builtin_amdgcn_mfma_f32_16x16x32_bf16(afh[i], bfl[j], acc[i][j], 0, 0, 0);
        acc[i][j] = __builtin_amdgcn_mfma_f32_16x16x32_bf16(afl[i], bfh[j], acc[i][j], 0, 0, 0);
      }
    __syncthreads();
  }
#pragma unroll
  for (int i = 0; i < 4; i++)
#pragma unroll
    for (int j = 0; j < 4; j++) {
#pragma unroll
      for (int r = 0; r < 4; r++) {
        const int gr = rbase + wrow + i * 16 + quad * 4 + r;
        const int gc = outOff + obase + wcol + j * 16 + l15;
        Out[(size_t)gr * ldOut + gc] = acc[i][j][r];
      }
    }
  if (oparts) {
    const int O = gridDim.x * 128;
    __shared__ double scs[4][4][16], scq[4][4][16];
#pragma unroll
    for (int j = 0; j < 4; j++) {
      double s = 0., q = 0.;
#pragma unroll
      for (int i = 0; i < 4; i++)
#pragma unroll
        for (int r = 0; r < 4; r++) {
          double v = (double)acc[i][j][r];
          s += v; q += v * v;
        }
      s += __shfl_down(s, 32); s += __shfl_down(s, 16);
      q += __shfl_down(q, 32); q += __shfl_down(q, 16);
      if (lane < 16) { scs[wave][j][lane] = s; scq[wave][j][lane] = q; }
    }
    __syncthreads();
    if (tid < 128) {
      const int c = tid;
      const int half = c >> 6, jj = (c & 63) >> 4, l = c & 15;
      const int wA = half, wB = half + 2;
      double s = scs[wA][jj][l] + scs[wB][jj][l];
      double q = scq[wA][jj][l] + scq[wB][jj][l];
      const size_t p = ((size_t)blockIdx.y * O + obase + c) * 2;
      oparts[p] = s;
      oparts[p + 1] = q;
    }
    __threadfence();
    __syncthreads();
    __shared__ u32 isLast;
    if (tid == 0) isLast = (atomicAdd(counter, 1u) == gridDim.x * gridDim.y - 1);
    __syncthreads();
    if (isLast) {
      __threadfence();
      const volatile double* vp = (const volatile double*)oparts;
      for (int c = tid; c < O; c += 256) {
        double s = 0, q = 0;
        for (int y = 0; y < 64; y++) {
          const size_t p = ((size_t)y * O + c) * 2;
          s += vp[p]; q += vp[p + 1];
        }
        double mv = s / (double)RTOT;
        double var = q / (double)RTOT - mv * mv;
        omean[c] = (float)mv;
        oinv[c] = (float)(1.0 / sqrt(var + 1e-5));
      }
    }
  }
}

// -------- edge gather + fused last-block stats ------------------------------
__global__ __launch_bounds__(256) void edge_gather(
    const float* __restrict__ Y, const int* __restrict__ idx,
    float* __restrict__ dst, int dstS, int dstOff,
    double* __restrict__ parts, int O, u32* __restrict__ counter,
    float* __restrict__ smean, float* __restrict__ sinv) {
  const int NCH = 128;
  __shared__ int sidx[NCH * KNN16];
  __shared__ double sred[256 * 5];
  const int tid = threadIdx.x;
  const int row0 = blockIdx.x * NCH;
  const int OC = (O < 128) ? O : 128;
  const int subcnt = 256 / OC;
  const int olane = tid % OC;
  const int sub = tid / OC;
  const int o = blockIdx.y * 128 + olane;
  for (int i = tid; i < NCH * KNN16; i += 256) sidx[i] = idx[(size_t)row0 * KNN16 + i];
  __syncthreads();
  const int twoO = 2 * O;
  double s1 = 0, s2 = 0, scr = 0, sc = 0, sc2 = 0;
  for (int nl = sub; nl < NCH; nl += subcnt) {
    const int r = row0 + nl;
    const int bbase = (r >> 11) << 11;
    const int* ip = &sidx[nl * KNN16];
    float m = -INFINITY, a1 = 0.f, a2 = 0.f;
#pragma unroll
    for (int k = 0; k < KNN16; k++) {
      const int nb = ip[k];
      const float v = Y[(size_t)(bbase + nb) * twoO + o];
      m = fmaxf(m, v);
      a1 += v;
      a2 = fmaf(v, v, a2);
    }
    const float yc = Y[(size_t)r * twoO + O + o];
    dst[(size_t)r * dstS + dstOff + o] = yc + m;
    s1 += a1; s2 += a2; scr += (double)yc * (double)a1;
    sc += yc; sc2 += (double)yc * (double)yc;
  }
  sred[tid * 5 + 0] = s1; sred[tid * 5 + 1] = s2; sred[tid * 5 + 2] = scr;
  sred[tid * 5 + 3] = sc; sred[tid * 5 + 4] = sc2;
  __syncthreads();
  if (sub == 0) {
    for (int j = 1; j < subcnt; j++) {
      const int t2 = tid + j * OC;
      s1 += sred[t2 * 5 + 0]; s2 += sred[t2 * 5 + 1]; scr += sred[t2 * 5 + 2];
      sc += sred[t2 * 5 + 3]; sc2 += sred[t2 * 5 + 4];
    }
    double* pp = &parts[((size_t)blockIdx.x * O + o) * 5];
    pp[0] = s1; pp[1] = s2; pp[2] = scr; pp[3] = sc; pp[4] = sc2;
  }
  __threadfence();
  __syncthreads();
  __shared__ u32 isLast;
  if (tid == 0) isLast = (atomicAdd(counter, 1u) == gridDim.x * gridDim.y - 1);
  __syncthreads();
  if (isLast) {
    __threadfence();
    const volatile double* vp = (const volatile double*)parts;
    for (int oo = tid; oo < O; oo += 256) {
      double t1 = 0, t2 = 0, tcr = 0, tc = 0, tc2 = 0;
      for (int k = 0; k < 64; k++) {
        const size_t p = ((size_t)k * O + oo) * 5;
        t1 += vp[p]; t2 += vp[p + 1]; tcr += vp[p + 2]; tc += vp[p + 3]; tc2 += vp[p + 4];
      }
      const double cnt = (double)RTOT * KNN16;
      double mv = (t1 + (double)KNN16 * tc) / cnt;
      double ev2 = (t2 + 2.0 * tcr + (double)KNN16 * tc2) / cnt;
      smean[oo] = (float)mv;
      sinv[oo] = (float)(1.0 / sqrt(ev2 - mv * mv + 1e-5));
    }
  }
}

// -------- g = concat(max, mean) of lrelu(bn(h5)), fused final ---------------
__global__ __launch_bounds__(256) void reduce_bn(const float* __restrict__ H,
                                                 const float* __restrict__ m5,
                                                 const float* __restrict__ i5,
                                                 float* __restrict__ part,
                                                 float* __restrict__ g,
                                                 u32* __restrict__ counter) {
  const int chunk = blockIdx.x;  // 128 chunks of 64 rows
  const int row0 = chunk * 64;
  const int tid = threadIdx.x;
  float mx[4] = {-INFINITY, -INFINITY, -INFINITY, -INFINITY};
  float sm[4] = {0.f, 0.f, 0.f, 0.f};
  for (int nl = 0; nl < 64; nl++) {
    const float* row = &H[(size_t)(row0 + nl) * 1024];
#pragma unroll
    for (int oi = 0; oi < 4; oi++) {
      const int o = tid + oi * 256;
      float v = lrelu_f((row[o] - m5[o]) * i5[o]);
      mx[oi] = fmaxf(mx[oi], v);
      sm[oi] += v;
    }
  }
#pragma unroll
  for (int oi = 0; oi < 4; oi++) {
    part[(size_t)chunk * 2048 + tid + oi * 256] = mx[oi];
    part[(size_t)chunk * 2048 + 1024 + tid + oi * 256] = sm[oi];
  }
  __threadfence();
  __syncthreads();
  __shared__ u32 isLast;
  if (tid == 0) isLast = (atomicAdd(counter, 1u) == 127u);
  __syncthreads();
  if (isLast) {
    __threadfence();
    const volatile float* vp = (const volatile float*)part;
    for (int i = tid; i < 4096; i += 256) {
      int b = i >> 10, o = i & 1023;
      float mmx = -INFINITY, ssm = 0.f;
      for (int c = b * 32; c < b * 32 + 32; c++) {
        mmx = fmaxf(mmx, vp[(size_t)c * 2048 + o]);
        ssm += vp[(size_t)c * 2048 + 1024 + o];
      }
      g[b * 2048 + o] = mmx;
      g[b * 2048 + 1024 + o] = ssm * (1.0f / 2048.0f);
    }
  }
}

// -------- latent = lrelu(BN_over_batch(g @ W^T)) ----------------------------
__global__ __launch_bounds__(256) void linear1_bn(const float* __restrict__ g,
                                                  const float* __restrict__ W,
                                                  float* __restrict__ latent) {
  __shared__ __align__(16) float sg[4][2048];
  const int tid = threadIdx.x;
  for (int i = tid; i < 4 * 2048; i += 256) sg[i >> 11][i & 2047] = g[i];
  __syncthreads();
  const int wave = tid >> 6, lane = tid & 63;
  const int o = blockIdx.x * 4 + wave;
  const float* wr = &W[(size_t)o * 2048];
  float a0 = 0.f, a1 = 0.f, a2 = 0.f, a3 = 0.f;
  for (int k = lane * 4; k < 2048; k += 256) {
    float4 w4 = *(const float4*)&wr[k];
    float4 x0 = *(const float4*)&sg[0][k];
    float4 x1 = *(const float4*)&sg[1][k];
    float4 x2 = *(const float4*)&sg[2][k];
    float4 x3 = *(const float4*)&sg[3][k];
    a0 += w4.x * x0.x + w4.y * x0.y + w4.z * x0.z + w4.w * x0.w;
    a1 += w4.x * x1.x + w4.y * x1.y + w4.z * x1.z + w4.w * x1.w;
    a2 += w4.x * x2.x + w4.y * x2.y + w4.z * x2.z + w4.w * x2.w;
    a3 += w4.x * x3.x + w4.y * x3.y + w4.z * x3.z + w4.w * x3.w;
  }
  for (int s = 32; s > 0; s >>= 1) {
    a0 += __shfl_down(a0, s); a1 += __shfl_down(a1, s);
    a2 += __shfl_down(a2, s); a3 += __shfl_down(a3, s);
  }
  if (lane == 0) {
    float m = (a0 + a1 + a2 + a3) * 0.25f;
    float d0 = a0 - m, d1 = a1 - m, d2 = a2 - m, d3 = a3 - m;
    float var = (d0 * d0 + d1 * d1 + d2 * d2 + d3 * d3) * 0.25f;
    float inv = 1.0f / sqrtf(var + 1e-5f);
    latent[0 * 2048 + o] = lrelu_f(d0 * inv);
    latent[1 * 2048 + o] = lrelu_f(d1 * inv);
    latent[2 * 2048 + o] = lrelu_f(d2 * inv);
    latent[3 * 2048 + o] = lrelu_f(d3 * inv);
  }
}

// -------- generic fc: out[b][o] = act(dot(X[b], W[o]) + bias[o]) ------------
__global__ __launch_bounds__(256) void fc_wave(const float* __restrict__ X,
                                               const float* __restrict__ W,
                                               const float* __restrict__ bias,
                                               float* __restrict__ out,
                                               int K, int O, int relu) {
  extern __shared__ float sx[];
  const int tid = threadIdx.x;
  for (int i = tid; i < 4 * K; i += 256) sx[i] = X[i];
  __syncthreads();
  const int wave = tid >> 6, lane = tid & 63;
#pragma unroll
  for (int oi = 0; oi < 4; oi++) {
    const int o = blockIdx.x * 16 + wave * 4 + oi;
    if (o >= O) continue;
    const float* wr = &W[(size_t)o * K];
    float a0 = 0.f, a1 = 0.f, a2 = 0.f, a3 = 0.f;
    for (int k = lane * 4; k < K; k += 256) {
      float4 w4 = *(const float4*)&wr[k];
      float4 x0 = *(const float4*)&sx[0 * K + k];
      float4 x1 = *(const float4*)&sx[1 * K + k];
      float4 x2 = *(const float4*)&sx[2 * K + k];
      float4 x3 = *(const float4*)&sx[3 * K + k];
      a0 += w4.x * x0.x + w4.y * x0.y + w4.z * x0.z + w4.w * x0.w;
      a1 += w4.x * x1.x + w4.y * x1.y + w4.z * x1.z + w4.w * x1.w;
      a2 += w4.x * x2.x + w4.y * x2.y + w4.z * x2.z + w4.w * x2.w;
      a3 += w4.x * x3.x + w4.y * x3.y + w4.z * x3.z + w4.w * x3.w;
    }
    for (int s = 32; s > 0; s >>= 1) {
      a0 += __shfl_down(a0, s); a1 += __shfl_down(a1, s);
      a2 += __shfl_down(a2, s); a3 += __shfl_down(a3, s);
    }
    if (lane == 0) {
      float bb = bias[o];
      float v0 = a0 + bb, v1 = a1 + bb, v2 = a2 + bb, v3 = a3 + bb;
      if (relu) {
        v0 = fmaxf(v0, 0.f); v1 = fmaxf(v1, 0.f);
        v2 = fmaxf(v2, 0.f); v3 = fmaxf(v3, 0.f);
      }
      out[0 * O + o] = v0; out[1 * O + o] = v1;
      out[2 * O + o] = v2; out[3 * O + o] = v3;
    }
  }
}

// -------- fc3 + fc3_1 fused (single block) ----------------------------------
__global__ __launch_bounds__(256) void fc_tail1(const float* __restrict__ x2v,
                                                const float* __restrict__ w3,
                                                const float* __restrict__ b3,
                                                const float* __restrict__ w31,
                                                const float* __restrict__ b31,
                                                float* __restrict__ pc1) {
  __shared__ float sx2[4 * 512];
  __shared__ float sx3[4 * 256];
  const int tid = threadIdx.x;
  for (int i = tid; i < 2048; i += 256) sx2[i] = x2v[i];
  __syncthreads();
  {
    const int o = tid;
    const float* wr = &w3[(size_t)o * 512];
    float a0 = 0.f, a1 = 0.f, a2 = 0.f, a3 = 0.f;
    for (int k = 0; k < 512; k += 4) {
      float4 w4 = *(const float4*)&wr[k];
      float4 x0 = *(const float4*)&sx2[0 * 512 + k];
      float4 x1 = *(const float4*)&sx2[1 * 512 + k];
      float4 x2 = *(const float4*)&sx2[2 * 512 + k];
      float4 x3 = *(const float4*)&sx2[3 * 512 + k];
      a0 += w4.x * x0.x + w4.y * x0.y + w4.z * x0.z + w4.w * x0.w;
      a1 += w4.x * x1.x + w4.y * x1.y + w4.z * x1.z + w4.w * x1.w;
      a2 += w4.x * x2.x + w4.y * x2.y + w4.z * x2.z + w4.w * x2.w;
      a3 += w4.x * x3.x + w4.y * x3.y + w4.z * x3.z + w4.w * x3.w;
    }
    float bb = b3[o];
    sx3[0 * 256 + o] = fmaxf(a0 + bb, 0.f);
    sx3[1 * 256 + o] = fmaxf(a1 + bb, 0.f);
    sx3[2 * 256 + o] = fmaxf(a2 + bb, 0.f);
    sx3[3 * 256 + o] = fmaxf(a3 + bb, 0.f);
  }
  __syncthreads();
  if (tid < 192) {
    const int o = tid;
    const float* wr = &w31[(size_t)o * 256];
    float a0 = 0.f, a1 = 0.f, a2 = 0.f, a3 = 0.f;
    for (int k = 0; k < 256; k += 4) {
      float4 w4 = *(const float4*)&wr[k];
      float4 x0 = *(const float4*)&sx3[0 * 256 + k];
      float4 x1 = *(const float4*)&sx3[1 * 256 + k];
      float4 x2 = *(const float4*)&sx3[2 * 256 + k];
      float4 x3 = *(const float4*)&sx3[3 * 256 + k];
      a0 += w4.x * x0.x + w4.y * x0.y + w4.z * x0.z + w4.w * x0.w;
      a1 += w4.x * x1.x + w4.y * x1.y + w4.z * x1.z + w4.w * x1.w;
      a2 += w4.x * x2.x + w4.y * x2.y + w4.z * x2.z + w4.w * x2.w;
      a3 += w4.x * x3.x + w4.y * x3.y + w4.z * x3.z + w4.w * x3.w;
    }
    float bb = b31[o];
    pc1[0 * 192 + o] = a0 + bb;
    pc1[1 * 192 + o] = a1 + bb;
    pc1[2 * 192 + o] = a2 + bb;
    pc1[3 * 192 + o] = a3 + bb;
  }
}

// -------- decoder convs + mirror expansions + all outputs (1 dispatch) ------
__global__ __launch_bounds__(256) void tail_kernel(
    const float* __restrict__ pc1, const float* __restrict__ pc2f,
    const float* __restrict__ pc3f,
    const float* __restrict__ w21, const float* __restrict__ b21,
    const float* __restrict__ w11, const float* __restrict__ b11,
    const float* __restrict__ w12, const float* __restrict__ b12,
    float* __restrict__ out) {
  const int b = blockIdx.x >> 4, jc = blockIdx.x & 15, j0 = jc * 32;
  __shared__ float p2f[64][128];   // 32KB
  __shared__ float p3f[128][32];   // 16KB
  __shared__ float p3g[64][32];    // 8KB
  __shared__ float p2x[3][128];
  __shared__ float p3x[3][32];
  __shared__ float p1s[3][64];
  const int tid = threadIdx.x;
  for (int t = tid; t < 8192; t += 256) p2f[t >> 7][t & 127] = pc2f[(size_t)b * 8192 + t];
  for (int t = tid; t < 4096; t += 256)
    p3f[t >> 5][t & 31] = pc3f[(size_t)b * 65536 + (size_t)(t >> 5) * 512 + j0 + (t & 31)];
  if (tid < 192) p1s[tid >> 6][tid & 63] = pc1[b * 192 + tid];
  __syncthreads();
  for (int t = tid; t < 384; t += 256) {
    const int o = t / 128, j = t % 128;
    float a = b21[o];
    for (int c = 0; c < 64; c++) a = fmaf(w21[o * 64 + c], p2f[c][j], a);
    p2x[o][j] = a;
  }
  for (int t = tid; t < 2048; t += 256) {
    const int o = t >> 5, j = t & 31;
    float a = b11[o];
    for (int c = 0; c < 128; c++) a = fmaf(w11[o * 128 + c], p3f[c][j], a);
    p3g[o][j] = fmaxf(a, 0.f);
  }
  __syncthreads();
  for (int t = tid; t < 96; t += 256) {
    const int o = t / 32, j = t % 32;
    float a = b12[o];
    for (int c = 0; c < 64; c++) a = fmaf(w12[o * 64 + c], p3g[c][j], a);
    p3x[o][j] = a;
  }
  __syncthreads();
  if (jc == 0) {
    for (int i = tid; i < 192; i += 256) {
      int pt = i / 3, c = i % 3;
      out[b * 192 + i] = p1s[c][pt];
    }
    if (tid < 64) {
      const int i = tid;
      float xs0 = p1s[0][i], xs1 = p1s[1][i], xs2 = p1s[2][i];
      float xxi = xs0 * xs0 + xs1 * xs1 + xs2 * xs2;
      float bestv = -INFINITY;
      int besti = 0;
      for (int m = 0; m < 64; m++) {
        float q0 = p1s[0][m], q1 = p1s[1][m], q2 = p1s[2][m];
        float dot = xs0 * q0 + xs1 * q1 + xs2 * q2;
        float inner = -2.0f * dot;
        float pd = -xxi - inner - (q0 * q0 + q1 * q1 + q2 * q2);
        if (pd > bestv) { bestv = pd; besti = m; }
      }
#pragma unroll
      for (int c = 0; c < 3; c++) {
        float ctr = p1s[c][i];
        float nb = p1s[c][besti];
        out[768 + b * 384 + (2 * i) * 3 + c] = (2.0f * ctr - nb) + p2x[c][2 * i];
        out[768 + b * 384 + (2 * i + 1) * 3 + c] = ctr + p2x[c][2 * i + 1];
      }
    }
  }
  if (tid < 8) {
    const int q = jc * 8 + tid;
    float xs0 = p2x[0][q], xs1 = p2x[1][q], xs2 = p2x[2][q];
    float xxj = xs0 * xs0 + xs1 * xs1 + xs2 * xs2;
    float bv0 = -INFINITY, bv1 = -INFINITY, bv2 = -INFINITY;
    int bi0 = 0, bi1 = 0, bi2 = 0;
    for (int m = 0; m < 128; m++) {
      float q0 = p2x[0][m], q1 = p2x[1][m], q2 = p2x[2][m];
      float dot = xs0 * q0 + xs1 * q1 + xs2 * q2;
      float inner = -2.0f * dot;
      float pd = -xxj - inner - (q0 * q0 + q1 * q1 + q2 * q2);
      if (pd > bv2) {
        bv2 = pd; bi2 = m;
        if (bv2 > bv1) { float t = bv2; bv2 = bv1; bv1 = t; int ti = bi2; bi2 = bi1; bi1 = ti; }
        if (bv1 > bv0) { float t = bv1; bv1 = bv0; bv0 = t; int ti = bi1; bi1 = bi0; bi0 = ti; }
      }
    }
#pragma unroll
    for (int c = 0; c < 3; c++) {
      float ctr = p2x[c][q];
      float e[4];
      e[0] = 2.0f * ctr - p2x[c][bi0];
      e[1] = 2.0f * ctr - p2x[c][bi1];
      e[2] = 2.0f * ctr - p2x[c][bi2];
      e[3] = ctr;
#pragma unroll
      for (int r = 0; r < 4; r++) {
        const int jg = 4 * q + r;
        out[2304 + b * 1536 + jg * 3 + c] = e[r] + p3x[c][jg - j0];
      }
    }
  }
}

extern "C" void kernel_launch(void* const* d_in, const int* in_sizes, int n_in,
                              void* d_out, int out_size, void* d_ws, size_t ws_size,
                              hipStream_t stream) {
  (void)in_sizes; (void)n_in; (void)out_size; (void)ws_size;
  const float* x          = (const float*)d_in[0];
  const float* conv1_w    = (const float*)d_in[1];
  const float* conv2_w    = (const float*)d_in[2];
  const float* conv2_1_w  = (const float*)d_in[3];
  const float* conv3_w    = (const float*)d_in[4];
  const float* conv3_1_w  = (const float*)d_in[5];
  const float* conv4_w    = (const float*)d_in[6];
  const float* conv5_w    = (const float*)d_in[7];
  const float* linear1_w  = (const float*)d_in[8];
  const float* fc1_w      = (const float*)d_in[9];
  const float* fc1_b      = (const float*)d_in[10];
  const float* fc2_w      = (const float*)d_in[11];
  const float* fc2_b      = (const float*)d_in[12];
  const float* fc3_w      = (const float*)d_in[13];
  const float* fc3_b      = (const float*)d_in[14];
  const float* fc1_1_w    = (const float*)d_in[15];
  const float* fc1_1_b    = (const float*)d_in[16];
  const float* fc2_1_w    = (const float*)d_in[17];
  const float* fc2_1_b    = (const float*)d_in[18];
  const float* fc3_1_w    = (const float*)d_in[19];
  const float* fc3_1_b    = (const float*)d_in[20];
  const float* g_conv1_1_w = (const float*)d_in[21];
  const float* g_conv1_1_b = (const float*)d_in[22];
  const float* g_conv1_2_w = (const float*)d_in[23];
  const float* g_conv1_2_b = (const float*)d_in[24];
  const float* g_conv2_1_w = (const float*)d_in[25];
  const float* g_conv2_1_b = (const float*)d_in[26];

  char* ws = (char*)d_ws;
  size_t off = 0;
  auto alloc = [&](size_t bytes) -> void* {
    off = (off + 511) & ~((size_t)511);
    void* p = ws + off;
    off += bytes;
    return p;
  };

  int*    idx0   = (int*)alloc((size_t)RTOT * 16 * 4);
  u64*    pkeys  = (u64*)alloc((size_t)RTOT * 128 * 8);
  float*  ws1    = (float*)alloc((size_t)384 * 4);
  float*  ydyc   = (float*)alloc((size_t)RTOT * 1024 * 4);
  float*  xcat   = (float*)alloc((size_t)RTOT * 768 * 4);
  float*  h1     = (float*)alloc((size_t)RTOT * 128 * 4);
  float*  h2     = (float*)alloc((size_t)RTOT * 256 * 4);
  float*  h5     = (float*)alloc((size_t)RTOT * 1024 * 4);
  double* gparts = (double*)alloc((size_t)64 * 512 * 5 * 8);
  double* oparts = (double*)alloc((size_t)64 * 1024 * 2 * 8);
  u32*    ctrs   = (u32*)alloc(16 * 4);
  float*  xm     = (float*)alloc(768 * 4);
  float*  xiv    = (float*)alloc(768 * 4);
  float*  hm1    = (float*)alloc(128 * 4);
  float*  hiv1   = (float*)alloc(128 * 4);
  float*  hm2    = (float*)alloc(256 * 4);
  float*  hiv2   = (float*)alloc(256 * 4);
  float*  hm5    = (float*)alloc(1024 * 4);
  float*  hiv5   = (float*)alloc(1024 * 4);
  float*  gpart  = (float*)alloc((size_t)128 * 2048 * 4);
  float*  gvec   = (float*)alloc((size_t)4 * 2048 * 4);
  float*  latent = (float*)alloc((size_t)4 * 2048 * 4);
  float*  x1v    = (float*)alloc((size_t)4 * 1024 * 4);
  float*  x2v    = (float*)alloc((size_t)4 * 512 * 4);
  float*  pc1    = (float*)alloc((size_t)4 * 192 * 4);
  float*  pc2f   = (float*)alloc((size_t)4 * 8192 * 4);
  float*  pc3f   = (float*)alloc((size_t)4 * 65536 * 4);
  // split weights
  ush* ws2hi = (ush*)alloc((size_t)8192 * 2);
  ush* ws2lo = (ush*)alloc((size_t)8192 * 2);
  ush* ws3hi = (ush*)alloc((size_t)32768 * 2);
  ush* ws3lo = (ush*)alloc((size_t)32768 * 2);
  ush* ws4hi = (ush*)alloc((size_t)262144 * 2);
  ush* ws4lo = (ush*)alloc((size_t)262144 * 2);
  ush* c21hi = (ush*)alloc((size_t)16384 * 2);
  ush* c21lo = (ush*)alloc((size_t)16384 * 2);
  ush* c31hi = (ush*)alloc((size_t)65536 * 2);
  ush* c31lo = (ush*)alloc((size_t)65536 * 2);
  ush* c5hi  = (ush*)alloc((size_t)786432 * 2);
  ush* c5lo  = (ush*)alloc((size_t)786432 * 2);

  // 1) weight preps + counter zeroing
  prep_all<<<4578, 256, 0, stream>>>(conv1_w, conv2_w, conv2_1_w, conv3_w, conv3_1_w,
                                     conv4_w, conv5_w, ws1, ws2hi, ws2lo, ws3hi, ws3lo,
                                     ws4hi, ws4lo, c21hi, c21lo, c31hi, c31lo, c5hi, c5lo, ctrs);
  // 2-3) KNN
  knn16_part<<<dim3(8, 8, 4), 256, 0, stream>>>(x, pkeys);
  knn16_merge<<<RTOT / 256, 256, 0, stream>>>(pkeys, idx0);
  // 4) conv1 fused -> xcat[:,0:64) + stats
  edge_conv1<<<64, 256, 0, stream>>>(x, idx0, ws1, xcat, gparts, ctrs + CTR_G1, xm, xiv);
  // 5-6) conv2
  gemm_bn<<<dim3(1, 64), 256, 0, stream>>>(xcat, 768, xm, xiv, ws2hi, ws2lo,
                                           ydyc, 128, 0, 64, nullptr, nullptr, nullptr, nullptr);
  edge_gather<<<dim3(64, 1), 256, 0, stream>>>(ydyc, idx0, xcat, 768, 64, gparts, 64,
                                               ctrs + CTR_G2, xm + 64, xiv + 64);
  // 7) conv2_1 -> h1 (+stats)
  gemm_bn<<<dim3(1, 64), 256, 0, stream>>>(xcat, 768, xm, xiv, c21hi, c21lo,
                                           h1, 128, 0, 128, oparts, ctrs + CTR_M21, hm1, hiv1);
  // 8-9) conv3
  gemm_bn<<<dim3(2, 64), 256, 0, stream>>>(h1, 128, hm1, hiv1, ws3hi, ws3lo,
                                           ydyc, 256, 0, 128, nullptr, nullptr, nullptr, nullptr);
  edge_gather<<<dim3(64, 1), 256, 0, stream>>>(ydyc, idx0, xcat, 768, 128, gparts, 128,
                                               ctrs + CTR_G3, xm + 128, xiv + 128);
  // 10) conv3_1 -> h2 (+stats)
  gemm_bn<<<dim3(2, 64), 256, 0, stream>>>(xcat, 768, xm, xiv, c31hi, c31lo,
                                           h2, 256, 0, 256, oparts, ctrs + CTR_M31, hm2, hiv2);
  // 11-12) conv4
  gemm_bn<<<dim3(8, 64), 256, 0, stream>>>(h2, 256, hm2, hiv2, ws4hi, ws4lo,
                                           ydyc, 1024, 0, 256, nullptr, nullptr, nullptr, nullptr);
  edge_gather<<<dim3(64, 4), 256, 0, stream>>>(ydyc, idx0, xcat, 768, 256, gparts, 512,
                                               ctrs + CTR_G4, xm + 256, xiv + 256);
  // 13) conv5 -> h5 (+stats)
  gemm_bn<<<dim3(8, 64), 256, 0, stream>>>(xcat, 768, xm, xiv, c5hi, c5lo,
                                           h5, 1024, 0, 768, oparts, ctrs + CTR_M5, hm5, hiv5);
  // 14) g = concat(max, mean) with inline BN
  reduce_bn<<<128, 256, 0, stream>>>(h5, hm5, hiv5, gpart, gvec, ctrs + CTR_RED);
  // 15) latent
  linear1_bn<<<512, 256, 0, stream>>>(gvec, linear1_w, latent);
  // 16-19) fc chain
  fc_wave<<<1024 / 16, 256, 4 * 2048 * 4, stream>>>(latent, fc1_w, fc1_b, x1v, 2048, 1024, 1);
  fc_wave<<<512 / 16, 256, 4 * 1024 * 4, stream>>>(x1v, fc2_w, fc2_b, x2v, 1024, 512, 1);
  fc_tail1<<<1, 256, 0, stream>>>(x2v, fc3_w, fc3_b, fc3_1_w, fc3_1_b, pc1);
  fc_wave<<<8192 / 16, 256, 4 * 512 * 4, stream>>>(x2v, fc2_1_w, fc2_1_b, pc2f, 512, 8192, 1);
  fc_wave<<<65536 / 16, 256, 4 * 1024 * 4, stream>>>(x1v, fc1_1_w, fc1_1_b, pc3f, 1024, 65536, 1);
  // 20) decoder convs + expansions + outputs
  tail_kernel<<<64, 256, 0, stream>>>(pc1, pc2f, pc3f, g_conv2_1_w, g_conv2_1_b,
                                      g_conv1_1_w, g_conv1_1_b, g_conv1_2_w, g_conv1_2_b,
                                      (float*)d_out);
}